// Round 9
// baseline (798.378 us; speedup 1.0000x reference)
//
#include <hip/hip_runtime.h>
#include <hip/hip_fp16.h>

// GCN critic: 4 layers (128->16->16->16->1), symmetric gcn_norm with self-loops,
// global mean pool. N=100000 nodes, E=6400000 edges.
// R8: line-aligned padded (block,bucket) reservations (kills fill write-line
// amplification), split 6B pre-sort records (epm uint meta + epw fp16 w),
// 4B post-sort records (src<<15|fp16w) written in place. Holes are w=0 records.

#define BSHIFT 7
#define BSIZE 128            // nodes per dst bucket
#define NBUCK_ALLOC 800      // >= nbuck = ceil(100000/128) = 782
#define CAPB 12288           // max padded records per bucket (8192 + ~2940 holes + tail)
#define NSRC_MASK 131071     // 17-bit src (src < 131072)
#define BLKB 512
#define CHUNKE 32768         // edges per hist/fill block
#define PADQ 16              // reservation quantum (records) -> 64B epm lines

static __device__ __forceinline__ float relu_(float v) { return v > 0.f ? v : 0.f; }

static __device__ __forceinline__ float h2f_bits(unsigned short b) {
    __half_raw hr; hr.x = b;
    return __half2float(__half(hr));
}
static __device__ __forceinline__ unsigned short f2h_bits(float f) {
    __half h = __float2half(f);
    __half_raw hr = *(__half_raw*)&h;
    return hr.x;
}

// ---- zero bucket counters ----
__global__ __launch_bounds__(256) void k_zero(int* __restrict__ gbcnt, int nbuck) {
    int i = blockIdx.x * 256 + threadIdx.x;
    if (i < nbuck) gbcnt[i] = 0;
}

// ---- stage A pass 1: per-block LDS histogram, accumulate PADDED counts ----
__global__ __launch_bounds__(BLKB) void k_histA(const int* __restrict__ dst, int* __restrict__ gbcnt,
                                                int E, int nbuck) {
    __shared__ int hist[NBUCK_ALLOC];
    const int t = threadIdx.x;
    for (int i = t; i < nbuck; i += BLKB) hist[i] = 0;
    __syncthreads();
    const int c0 = blockIdx.x * CHUNKE;
    const int c1 = min(c0 + CHUNKE, E);
    for (int e = c0 + t; e < c1; e += BLKB)
        atomicAdd(&hist[dst[e] >> BSHIFT], 1);
    __syncthreads();
    for (int i = t; i < nbuck; i += BLKB) {
        int h = hist[i];
        if (h) atomicAdd(&gbcnt[i], (h + PADQ - 1) & ~(PADQ - 1));
    }
}

// ---- stage A scan: brow (exclusive over padded counts) + bcur copy; one block ----
__global__ __launch_bounds__(1024) void k_scanA(const int* __restrict__ gbcnt, int* __restrict__ brow,
                                                int* __restrict__ bcur, int nbuck) {
    __shared__ int ps[1024];
    const int t = threadIdx.x;
    int i0 = t * 2, i1 = t * 2 + 1;
    int v0 = (i0 < nbuck) ? gbcnt[i0] : 0;
    int v1 = (i1 < nbuck) ? gbcnt[i1] : 0;
    int loc = v0 + v1;
    ps[t] = loc;
    __syncthreads();
    for (int o = 1; o < 1024; o <<= 1) {
        int x = 0;
        if (t >= o) x = ps[t - o];
        __syncthreads();
        ps[t] += x;
        __syncthreads();
    }
    int run = ps[t] - loc;
    if (i0 < nbuck) { brow[i0] = run; bcur[i0] = run; }
    if (i1 < nbuck) { brow[i1] = run + v0; bcur[i1] = run + v0; }
    if (t == 1023) brow[nbuck] = ps[1023];   // padded total
}

// ---- stage A pass 2: fill. epm = dstloc<<17|src, epw = fp16(w). Padded, line-exclusive. ----
__global__ __launch_bounds__(BLKB) void k_fillA(const int* __restrict__ src, const int* __restrict__ dst,
                                                const float* __restrict__ w, int* __restrict__ bcur,
                                                unsigned* __restrict__ epm, unsigned short* __restrict__ epw,
                                                int E, int nbuck) {
    __shared__ int hist[NBUCK_ALLOC];
    __shared__ int resv[NBUCK_ALLOC];
    __shared__ int cur[NBUCK_ALLOC];
    const int t = threadIdx.x;
    for (int i = t; i < nbuck; i += BLKB) hist[i] = 0;
    __syncthreads();
    const int c0 = blockIdx.x * CHUNKE;
    const int c1 = min(c0 + CHUNKE, E);
    for (int e = c0 + t; e < c1; e += BLKB)
        atomicAdd(&hist[dst[e] >> BSHIFT], 1);
    __syncthreads();
    for (int i = t; i < nbuck; i += BLKB) {
        int h = hist[i];
        int hp = (h + PADQ - 1) & ~(PADQ - 1);
        int base = hp ? atomicAdd(&bcur[i], hp) : 0;   // multiple of PADQ -> line-aligned
        resv[i] = base;
        cur[i] = base;
    }
    __syncthreads();
    for (int e = c0 + t; e < c1; e += BLKB) {
        int d = dst[e], s = src[e];
        int b = d >> BSHIFT;
        int pos = atomicAdd(&cur[b], 1);
        epm[pos] = ((unsigned)(d & (BSIZE - 1)) << 17) | (unsigned)s;
        epw[pos] = f2h_bits(w[e]);
    }
    __syncthreads();
    // fill holes (w=0, dstloc spread for balance) to complete every line
    for (int i = t; i < nbuck; i += BLKB) {
        int h = hist[i];
        if (!h) continue;
        int hp = (h + PADQ - 1) & ~(PADQ - 1);
        int b0 = resv[i];
        for (int p = b0 + h; p < b0 + hp; ++p) {
            epm[p] = ((unsigned)(p & (BSIZE - 1))) << 17;
            epw[p] = 0;
        }
    }
}

// ---- stage B: in-bucket sort by dstloc; emits 4B post-sort recs (src<<15|w15) in place
// into epm; also deg/dis + per-node rowptr2. ----
__global__ __launch_bounds__(BLKB) void k_sortB(unsigned* __restrict__ epm, const unsigned short* __restrict__ epw,
                                                const int* __restrict__ brow, float* __restrict__ dis,
                                                int* __restrict__ rowptr2, int n) {
    __shared__ unsigned stg[CAPB];         // 48 KB
    __shared__ int hist[BSIZE];
    __shared__ int excl[BSIZE];
    __shared__ int cur[BSIZE];
    __shared__ float degl[BSIZE];
    const int b = blockIdx.x, t = threadIdx.x;
    if (t < BSIZE) { hist[t] = 0; degl[t] = 0.f; }
    __syncthreads();
    const int base = brow[b];
    const int cnt = min(brow[b + 1] - base, CAPB);
    // pass 1: histogram + weighted degree (holes: w=0)
    for (int e = t; e < cnt; e += BLKB) {
        unsigned m = epm[base + e];
        int dl = m >> 17;
        atomicAdd(&hist[dl], 1);
        atomicAdd(&degl[dl], h2f_bits(epw[base + e]));
    }
    __syncthreads();
    if (t == 0) {
        int run = 0;
        for (int k = 0; k < BSIZE; ++k) { excl[k] = run; run += hist[k]; }
    }
    __syncthreads();
    if (t < BSIZE) {
        cur[t] = excl[t];
        int node = (b << BSHIFT) + t;
        if (node < n) {
            dis[node] = (float)(1.0 / sqrt((double)(degl[t] + 1.0f)));   // +1 self-loop
            rowptr2[node] = base + excl[t];
            if (node == n - 1) rowptr2[n] = base + excl[t] + hist[t];
        }
    }
    __syncthreads();
    // pass 2: compress + scatter into LDS at sorted position
    for (int e = t; e < cnt; e += BLKB) {
        unsigned m = epm[base + e];
        unsigned rec = (((unsigned)(m & NSRC_MASK)) << 15) | (unsigned)(epw[base + e] & 0x7FFF);
        int pos = atomicAdd(&cur[m >> 17], 1);
        stg[pos] = rec;
    }
    __syncthreads();
    // write back coalesced (in place over epm)
    for (int i = t; i < cnt; i += BLKB) epm[base + i] = stg[i];
}

// ---- dense: zs = fp16( dis * (act(xin) @ W) ) ; act = relu(x + bprev) if RELU ----
template<int FI, int FO, bool RELU>
__global__ __launch_bounds__(256) void k_dense(const float* __restrict__ xin, const float* __restrict__ W,
                                               const float* __restrict__ bprev, const float* __restrict__ dis,
                                               __half* __restrict__ zs, int n) {
    constexpr int NPB = 256 / FO;
    constexpr int XP = FI + 1;
    __shared__ float Wl[FI * FO];
    __shared__ float xs[NPB * XP];
    const int t = threadIdx.x;
    for (int i = t; i < FI * FO; i += 256) Wl[i] = W[i];
    const int node0 = blockIdx.x * NPB;
    for (int i = t; i < NPB * FI; i += 256) {
        int r = i / FI, c = i - r * FI;
        int node = node0 + r;
        float v = 0.f;
        if (node < n) {
            v = xin[node * FI + c];
            if constexpr (RELU) v = relu_(v + bprev[c]);
        }
        xs[r * XP + c] = v;
    }
    __syncthreads();
    const int r = t / FO, j = t - r * FO;
    const int node = node0 + r;
    if (node < n) {
        float s = 0.f;
#pragma unroll
        for (int k = 0; k < FI; ++k) s += xs[r * XP + k] * Wl[k * FO + j];
        zs[node * FO + j] = __float2half(s * dis[node]);
    }
}

// ---- aggregation FO=16: one wave per node, register accum, 4 independent load chains
// acc[d] = dis[d] * ( zs[d] + sum_e w_e * zs[src_e] )   (rec = src<<15|w15) ----
__global__ __launch_bounds__(256) void k_agg16(const unsigned* __restrict__ ep, const int* __restrict__ rowptr2,
                                               const float* __restrict__ dis, const __half* __restrict__ zs,
                                               float* __restrict__ acc, int n) {
    const int wv = (blockIdx.x * 256 + threadIdx.x) >> 6;   // node
    if (wv >= n) return;
    const int lane = threadIdx.x & 63;
    const int j = lane & 15, g = lane >> 4;
    const int base = rowptr2[wv], end = rowptr2[wv + 1];
    float s = 0.f;
    int e = base + g;
    for (; e + 12 < end; e += 16) {     // 4 independent rec->zs chains
        unsigned r0 = ep[e], r1 = ep[e + 4], r2 = ep[e + 8], r3 = ep[e + 12];
        float z0 = __half2float(zs[(r0 >> 15) * 16 + j]);
        float z1v = __half2float(zs[(r1 >> 15) * 16 + j]);
        float z2 = __half2float(zs[(r2 >> 15) * 16 + j]);
        float z3 = __half2float(zs[(r3 >> 15) * 16 + j]);
        s += z0 * h2f_bits((unsigned short)(r0 & 0x7FFF));
        s += z1v * h2f_bits((unsigned short)(r1 & 0x7FFF));
        s += z2 * h2f_bits((unsigned short)(r2 & 0x7FFF));
        s += z3 * h2f_bits((unsigned short)(r3 & 0x7FFF));
    }
    for (; e < end; e += 4) {
        unsigned r0 = ep[e];
        s += __half2float(zs[(r0 >> 15) * 16 + j]) * h2f_bits((unsigned short)(r0 & 0x7FFF));
    }
    s += __shfl_xor(s, 16, 64);
    s += __shfl_xor(s, 32, 64);
    if (g == 0) acc[wv * 16 + j] = dis[wv] * (__half2float(zs[wv * 16 + j]) + s);
}

// ---- aggregation FO=1 + relu+bias, per-block partial sums ----
__global__ __launch_bounds__(256) void k_agg1(const unsigned* __restrict__ ep, const int* __restrict__ rowptr2,
                                              const float* __restrict__ dis, const __half* __restrict__ zs1,
                                              const float* __restrict__ b4, float* __restrict__ partial, int n) {
    const int t = threadIdx.x;
    const int wv = (blockIdx.x * 256 + t) >> 6;
    const int lane = t & 63;
    float v = 0.f;
    if (wv < n) {
        const int base = rowptr2[wv], end = rowptr2[wv + 1];
        float s = 0.f;
        for (int e = base + lane; e < end; e += 64) {
            unsigned r = ep[e];
            s += __half2float(zs1[r >> 15]) * h2f_bits((unsigned short)(r & 0x7FFF));
        }
#pragma unroll
        for (int o = 32; o > 0; o >>= 1) s += __shfl_xor(s, o, 64);
        if (lane == 0) v = relu_(dis[wv] * (__half2float(zs1[wv]) + s) + b4[0]);
    }
    __shared__ float wsum[4];
    if (lane == 0) wsum[t >> 6] = v;
    __syncthreads();
    if (t == 0) partial[blockIdx.x] = wsum[0] + wsum[1] + wsum[2] + wsum[3];
}

// ---- final: out[0] = sum(partial) / n ; one block ----
__global__ __launch_bounds__(1024) void k_final(const float* __restrict__ partial, float* __restrict__ out,
                                                int nb, int n) {
    const int t = threadIdx.x;
    float s = 0.f;
    for (int i = t; i < nb; i += 1024) s += partial[i];
#pragma unroll
    for (int o = 32; o > 0; o >>= 1) s += __shfl_xor(s, o, 64);
    __shared__ float wsum[16];
    if ((t & 63) == 0) wsum[t >> 6] = s;
    __syncthreads();
    if (t == 0) {
        float tot = 0.f;
#pragma unroll
        for (int k = 0; k < 16; ++k) tot += wsum[k];
        out[0] = tot / (float)n;
    }
}

static inline size_t align_up(size_t x) { return (x + 255) & ~(size_t)255; }

extern "C" void kernel_launch(void* const* d_in, const int* in_sizes, int n_in,
                              void* d_out, int out_size, void* d_ws, size_t ws_size,
                              hipStream_t stream) {
    const float* vf  = (const float*)d_in[0];   // [N,128]
    const int*   edg = (const int*)d_in[1];     // [2,E] int32
    const float* w   = (const float*)d_in[2];   // [E]
    const float* W1  = (const float*)d_in[3];
    const float* b1  = (const float*)d_in[4];
    const float* W2  = (const float*)d_in[5];
    const float* b2  = (const float*)d_in[6];
    const float* W3  = (const float*)d_in[7];
    const float* b3  = (const float*)d_in[8];
    const float* W4  = (const float*)d_in[9];
    const float* b4  = (const float*)d_in[10];
    float* out = (float*)d_out;

    const int n = in_sizes[0] / 128;   // 100000
    const int E = in_sizes[2];         // 6400000
    const int* src = edg;
    const int* dst = edg + E;
    const int nbuck = (n + BSIZE - 1) >> BSHIFT;   // 782
    const int gB = (E + CHUNKE - 1) / CHUNKE;      // 196
    const size_t EPAD = (size_t)E + (size_t)gB * nbuck * PADQ + 1024;   // max padded records

    char* ws = (char*)d_ws;
    size_t off = 0;
    int*            gbcnt   = (int*)(ws + off);            off += align_up((size_t)nbuck * 4);
    int*            brow    = (int*)(ws + off);            off += align_up((size_t)(nbuck + 1) * 4);
    int*            bcur    = (int*)(ws + off);            off += align_up((size_t)nbuck * 4);
    int*            rowptr2 = (int*)(ws + off);            off += align_up((size_t)(n + 1) * 4);
    float*          dis     = (float*)(ws + off);          off += align_up((size_t)n * 4);
    float*          partial = (float*)(ws + off);          off += align_up((size_t)((n + 3) / 4 + 1) * 4);
    unsigned*       epm     = (unsigned*)(ws + off);       off += align_up(EPAD * 4);
    unsigned short* epw     = (unsigned short*)(ws + off); off += align_up(EPAD * 2);
    __half*         zsb     = (__half*)(ws + off);         off += align_up((size_t)n * 16 * 2);
    float*          acc     = (float*)(ws + off);          off += align_up((size_t)n * 16 * 4);
    __half*         zs1     = zsb;   // layer-4 dense output aliases zs (only n halves used)
    (void)ws_size;

    const int gD16 = (n + 15) / 16;                      // dense FO=16: 16 nodes/block
    const int gN = (n + 255) / 256;
    const int gW = (n + 3) / 4;                          // wave-per-node kernels

    k_zero<<<(nbuck + 255) / 256, 256, 0, stream>>>(gbcnt, nbuck);
    k_histA<<<gB, BLKB, 0, stream>>>(dst, gbcnt, E, nbuck);
    k_scanA<<<1, 1024, 0, stream>>>(gbcnt, brow, bcur, nbuck);
    k_fillA<<<gB, BLKB, 0, stream>>>(src, dst, w, bcur, epm, epw, E, nbuck);
    k_sortB<<<nbuck, BLKB, 0, stream>>>(epm, epw, brow, dis, rowptr2, n);

    // layer 1: 128 -> 16
    k_dense<128, 16, false><<<gD16, 256, 0, stream>>>(vf, W1, nullptr, dis, zsb, n);
    k_agg16<<<gW, 256, 0, stream>>>(epm, rowptr2, dis, zsb, acc, n);
    // layer 2: 16 -> 16
    k_dense<16, 16, true><<<gD16, 256, 0, stream>>>(acc, W2, b1, dis, zsb, n);
    k_agg16<<<gW, 256, 0, stream>>>(epm, rowptr2, dis, zsb, acc, n);
    // layer 3: 16 -> 16
    k_dense<16, 16, true><<<gD16, 256, 0, stream>>>(acc, W3, b2, dis, zsb, n);
    k_agg16<<<gW, 256, 0, stream>>>(epm, rowptr2, dis, zsb, acc, n);
    // layer 4: 16 -> 1, then aggregation + relu+bias into per-block partials
    k_dense<16, 1, true><<<gN, 256, 0, stream>>>(acc, W4, b3, dis, zs1, n);
    k_agg1<<<gW, 256, 0, stream>>>(epm, rowptr2, dis, zs1, b4, partial, n);
    k_final<<<1, 1024, 0, stream>>>(partial, out, gW, n);
}

// Round 10
// 603.009 us; speedup vs baseline: 1.3240x; 1.3240x over previous
//
#include <hip/hip_runtime.h>
#include <hip/hip_fp16.h>

// GCN critic: 4 layers (128->16->16->16->1), symmetric gcn_norm with self-loops,
// global mean pool. N=100000 nodes, E=6400000 edges.
// R9: LDS-staged bucket fill with coalesced full-line flush (kills write-line
// amplification), padded line-exclusive (block,bucket) reservations with w=0
// hole records, register-staged in-bucket sort -> 4B recs (src<<15|fp16w),
// per-node-wave register-accumulating aggregation. Zero per-edge global atomics.

#define BSHIFT 7
#define BSIZE 128            // nodes per dst bucket
#define NB_AL 800            // >= nbuck = ceil(100000/128) = 782
#define SCAN_N 1024          // scan width (pow2 >= nbuck)
#define CAPB 12288           // max padded records per bucket
#define NSRC_MASK 131071     // 17-bit src (src < 131072)
#define FBLK 512
#define FCHUNK 8192          // edges per hist/fill block
#define PADQ 8               // reservation quantum: 8 recs x 8B = one 64B line
#define SBLK 512
#define RPT (CAPB / SBLK)    // 24 records per thread in sortB

static __device__ __forceinline__ float relu_(float v) { return v > 0.f ? v : 0.f; }

static __device__ __forceinline__ float h2f_bits(unsigned short b) {
    __half_raw hr; hr.x = b;
    return __half2float(__half(hr));
}
static __device__ __forceinline__ unsigned short f2h_bits(float f) {
    __half h = __float2half(f);
    __half_raw hr = *(__half_raw*)&h;
    return hr.x;
}

// ---- zero bucket counters ----
__global__ __launch_bounds__(256) void k_zero(int* __restrict__ gbcnt, int nbuck) {
    int i = blockIdx.x * 256 + threadIdx.x;
    if (i < nbuck) gbcnt[i] = 0;
}

// ---- pass 1: per-block LDS histogram, accumulate PADDED per-block counts ----
__global__ __launch_bounds__(FBLK) void k_histA(const int* __restrict__ dst, int* __restrict__ gbcnt,
                                                int E, int nbuck) {
    __shared__ int hist[NB_AL];
    const int t = threadIdx.x;
    for (int i = t; i < nbuck; i += FBLK) hist[i] = 0;
    __syncthreads();
    const int c0 = blockIdx.x * FCHUNK;
    const int c1 = min(c0 + FCHUNK, E);
    for (int e = c0 + t; e < c1; e += FBLK)
        atomicAdd(&hist[dst[e] >> BSHIFT], 1);
    __syncthreads();
    for (int i = t; i < nbuck; i += FBLK) {
        int h = hist[i];
        if (h) atomicAdd(&gbcnt[i], (h + PADQ - 1) & ~(PADQ - 1));
    }
}

// ---- scan of padded counts: brow (exclusive) + bcur copy; one block ----
__global__ __launch_bounds__(1024) void k_scanA(const int* __restrict__ gbcnt, int* __restrict__ brow,
                                                int* __restrict__ bcur, int nbuck) {
    __shared__ int ps[1024];
    const int t = threadIdx.x;
    int i0 = t * 2, i1 = t * 2 + 1;
    int v0 = (i0 < nbuck) ? gbcnt[i0] : 0;
    int v1 = (i1 < nbuck) ? gbcnt[i1] : 0;
    int loc = v0 + v1;
    ps[t] = loc;
    __syncthreads();
    for (int o = 1; o < 1024; o <<= 1) {
        int x = 0;
        if (t >= o) x = ps[t - o];
        __syncthreads();
        ps[t] += x;
        __syncthreads();
    }
    int run = ps[t] - loc;
    if (i0 < nbuck) { brow[i0] = run; bcur[i0] = run; }
    if (i1 < nbuck) { brow[i1] = run + v0; bcur[i1] = run + v0; }
    if (t == 1023) brow[nbuck] = ps[1023];   // padded total
}

// ---- pass 2: LDS-staged fill. rec64 = fp16w<<32 | dstloc<<17 | src.
// Bucket-sorted staging in LDS, then flat coalesced flush of padded runs
// (full 64B lines, block-exclusive). Holes: w=0 records. ----
__global__ __launch_bounds__(FBLK) void k_fill(const int* __restrict__ src, const int* __restrict__ dst,
                                               const float* __restrict__ w, int* __restrict__ bcur,
                                               unsigned long long* __restrict__ ep, int E, int nbuck) {
    __shared__ unsigned long long stg[FCHUNK];   // 64 KB
    __shared__ int sc[SCAN_N];                   // packed (hp<<16)|cnt exclusive scan
    __shared__ int hist[NB_AL];
    __shared__ int cur[NB_AL];
    __shared__ int gbase[NB_AL];
    __shared__ int s_ptot;
    const int t = threadIdx.x;
    for (int i = t; i < nbuck; i += FBLK) hist[i] = 0;
    __syncthreads();
    const int c0 = blockIdx.x * FCHUNK;
    const int c1 = min(c0 + FCHUNK, E);
    for (int e = c0 + t; e < c1; e += FBLK)
        atomicAdd(&hist[dst[e] >> BSHIFT], 1);
    __syncthreads();
    // load packed values
    for (int i = t; i < SCAN_N; i += FBLK) {
        int c = (i < nbuck) ? hist[i] : 0;
        int hp = (c + PADQ - 1) & ~(PADQ - 1);
        sc[i] = (hp << 16) | c;
    }
    // Blelloch exclusive scan over SCAN_N
    for (int d = 1; d < SCAN_N; d <<= 1) {
        __syncthreads();
        int idx = (t + 1) * (d << 1) - 1;
        if (idx < SCAN_N) sc[idx] += sc[idx - d];
    }
    __syncthreads();
    if (t == 0) { s_ptot = sc[SCAN_N - 1]; sc[SCAN_N - 1] = 0; }
    for (int d = SCAN_N >> 1; d >= 1; d >>= 1) {
        __syncthreads();
        int idx = (t + 1) * (d << 1) - 1;
        if (idx < SCAN_N) { int tmp = sc[idx - d]; sc[idx - d] = sc[idx]; sc[idx] += tmp; }
    }
    __syncthreads();
    // reserve padded global ranges (line-aligned, block-exclusive) + init LDS cursors
    for (int i = t; i < nbuck; i += FBLK) {
        int c = hist[i];
        int hp = (c + PADQ - 1) & ~(PADQ - 1);
        gbase[i] = hp ? atomicAdd(&bcur[i], hp) : 0;
        cur[i] = sc[i] & 0xFFFF;   // lstart
    }
    __syncthreads();
    // scatter records into bucket-sorted LDS staging
    for (int e = c0 + t; e < c1; e += FBLK) {
        int d_ = dst[e];
        int b = d_ >> BSHIFT;
        int pos = atomicAdd(&cur[b], 1);
        stg[pos] = ((unsigned long long)f2h_bits(w[e]) << 32)
                 | ((unsigned)(d_ & (BSIZE - 1)) << 17) | (unsigned)src[e];
    }
    __syncthreads();
    // flat coalesced flush over padded total; binary search slot -> bucket
    const int ptot = s_ptot >> 16;
    for (int i = t; i < ptot; i += FBLK) {
        int lo = 0, hi = nbuck - 1;
        while (lo < hi) {
            int mid = (lo + hi + 1) >> 1;
            if ((sc[mid] >> 16) <= i) lo = mid; else hi = mid - 1;
        }
        int b = lo;
        int o = i - (sc[b] >> 16);
        int cb = hist[b];
        unsigned long long rec;
        if (o < cb) rec = stg[(sc[b] & 0xFFFF) + o];
        else rec = ((unsigned)(o & (BSIZE - 1))) << 17;   // hole: w=0
        ep[gbase[b] + o] = rec;
    }
}

// ---- stage B: register-staged in-bucket sort by dstloc; drops w=0 recs (holes);
// emits 4B recs (src<<15|w15) in place (upper half of own 8B region);
// deg/dis + per-node rs/re (in 4B-rec index units). ----
__global__ __launch_bounds__(SBLK) void k_sortB(unsigned long long* __restrict__ ep,
                                                const int* __restrict__ brow, float* __restrict__ dis,
                                                int* __restrict__ rs, int* __restrict__ re, int n) {
    __shared__ unsigned stg[CAPB];     // 48 KB
    __shared__ int hist[BSIZE];
    __shared__ int excl[BSIZE + 1];
    __shared__ int cur[BSIZE];
    __shared__ float degl[BSIZE];
    const int b = blockIdx.x, t = threadIdx.x;
    if (t < BSIZE) { hist[t] = 0; degl[t] = 0.f; }
    __syncthreads();
    const int base = brow[b];
    const int cnt = min(brow[b + 1] - base, CAPB);
    unsigned long long r[RPT];
#pragma unroll
    for (int k = 0; k < RPT; ++k) {
        int e = t + k * SBLK;
        if (e < cnt) r[k] = ep[base + e];
    }
    // pass 1: histogram + weighted degree (skip w=0: holes & null edges)
#pragma unroll
    for (int k = 0; k < RPT; ++k) {
        int e = t + k * SBLK;
        if (e < cnt) {
            unsigned w16 = (unsigned)(r[k] >> 32);
            if (w16) {
                int dl = ((unsigned)r[k] >> 17) & (BSIZE - 1);
                atomicAdd(&hist[dl], 1);
                atomicAdd(&degl[dl], h2f_bits((unsigned short)w16));
            }
        }
    }
    __syncthreads();
    if (t == 0) {
        int run = 0;
        for (int k2 = 0; k2 < BSIZE; ++k2) { excl[k2] = run; run += hist[k2]; }
        excl[BSIZE] = run;
    }
    __syncthreads();
    if (t < BSIZE) {
        cur[t] = excl[t];
        int node = (b << BSHIFT) + t;
        if (node < n) {
            dis[node] = (float)(1.0 / sqrt((double)(degl[t] + 1.0f)));   // +1 self-loop
            rs[node] = 2 * base + excl[t];          // 4B-rec index units
            re[node] = 2 * base + excl[t] + hist[t];
        }
    }
    __syncthreads();
    // pass 2: compress + scatter into LDS at sorted position
#pragma unroll
    for (int k = 0; k < RPT; ++k) {
        int e = t + k * SBLK;
        if (e < cnt) {
            unsigned w16 = (unsigned)(r[k] >> 32);
            if (w16) {
                int dl = ((unsigned)r[k] >> 17) & (BSIZE - 1);
                int pos = atomicAdd(&cur[dl], 1);
                stg[pos] = (((unsigned)r[k] & NSRC_MASK) << 15) | (w16 & 0x7FFF);
            }
        }
    }
    __syncthreads();
    // write back coalesced into the upper-aliased 4B view of OWN region (race-free)
    unsigned* outp = (unsigned*)(ep + base);
    const int m = excl[BSIZE];
    for (int i = t; i < m; i += SBLK) outp[i] = stg[i];
}

// ---- dense: zs = fp16( dis * (act(xin) @ W) ) ; act = relu(x + bprev) if RELU ----
template<int FI, int FO, bool RELU>
__global__ __launch_bounds__(256) void k_dense(const float* __restrict__ xin, const float* __restrict__ W,
                                               const float* __restrict__ bprev, const float* __restrict__ dis,
                                               __half* __restrict__ zs, int n) {
    constexpr int NPB = 256 / FO;
    constexpr int XP = FI + 1;
    __shared__ float Wl[FI * FO];
    __shared__ float xs[NPB * XP];
    const int t = threadIdx.x;
    for (int i = t; i < FI * FO; i += 256) Wl[i] = W[i];
    const int node0 = blockIdx.x * NPB;
    for (int i = t; i < NPB * FI; i += 256) {
        int r = i / FI, c = i - r * FI;
        int node = node0 + r;
        float v = 0.f;
        if (node < n) {
            v = xin[node * FI + c];
            if constexpr (RELU) v = relu_(v + bprev[c]);
        }
        xs[r * XP + c] = v;
    }
    __syncthreads();
    const int r = t / FO, j = t - r * FO;
    const int node = node0 + r;
    if (node < n) {
        float s = 0.f;
#pragma unroll
        for (int k = 0; k < FI; ++k) s += xs[r * XP + k] * Wl[k * FO + j];
        zs[node * FO + j] = __float2half(s * dis[node]);
    }
}

// ---- aggregation FO=16: one wave per node, register accum, 4 independent load chains
// acc[d] = dis[d] * ( zs[d] + sum_e w_e * zs[src_e] )   (rec = src<<15|w15) ----
__global__ __launch_bounds__(256) void k_agg16(const unsigned* __restrict__ epc, const int* __restrict__ rs,
                                               const int* __restrict__ re, const float* __restrict__ dis,
                                               const __half* __restrict__ zs, float* __restrict__ acc, int n) {
    const int wv = (blockIdx.x * 256 + threadIdx.x) >> 6;   // node
    if (wv >= n) return;
    const int lane = threadIdx.x & 63;
    const int j = lane & 15, g = lane >> 4;
    const int base = rs[wv], end = re[wv];
    float s = 0.f;
    int e = base + g;
    for (; e + 12 < end; e += 16) {     // 4 independent rec->zs chains
        unsigned r0 = epc[e], r1 = epc[e + 4], r2 = epc[e + 8], r3 = epc[e + 12];
        float z0 = __half2float(zs[(r0 >> 15) * 16 + j]);
        float z1v = __half2float(zs[(r1 >> 15) * 16 + j]);
        float z2 = __half2float(zs[(r2 >> 15) * 16 + j]);
        float z3 = __half2float(zs[(r3 >> 15) * 16 + j]);
        s += z0 * h2f_bits((unsigned short)(r0 & 0x7FFF));
        s += z1v * h2f_bits((unsigned short)(r1 & 0x7FFF));
        s += z2 * h2f_bits((unsigned short)(r2 & 0x7FFF));
        s += z3 * h2f_bits((unsigned short)(r3 & 0x7FFF));
    }
    for (; e < end; e += 4) {
        unsigned r0 = epc[e];
        s += __half2float(zs[(r0 >> 15) * 16 + j]) * h2f_bits((unsigned short)(r0 & 0x7FFF));
    }
    s += __shfl_xor(s, 16, 64);
    s += __shfl_xor(s, 32, 64);
    if (g == 0) acc[wv * 16 + j] = dis[wv] * (__half2float(zs[wv * 16 + j]) + s);
}

// ---- aggregation FO=1 + relu+bias, per-block partial sums ----
__global__ __launch_bounds__(256) void k_agg1(const unsigned* __restrict__ epc, const int* __restrict__ rs,
                                              const int* __restrict__ re, const float* __restrict__ dis,
                                              const __half* __restrict__ zs1, const float* __restrict__ b4,
                                              float* __restrict__ partial, int n) {
    const int t = threadIdx.x;
    const int wv = (blockIdx.x * 256 + t) >> 6;
    const int lane = t & 63;
    float v = 0.f;
    if (wv < n) {
        const int base = rs[wv], end = re[wv];
        float s = 0.f;
        for (int e = base + lane; e < end; e += 64) {
            unsigned r = epc[e];
            s += __half2float(zs1[r >> 15]) * h2f_bits((unsigned short)(r & 0x7FFF));
        }
#pragma unroll
        for (int o = 32; o > 0; o >>= 1) s += __shfl_xor(s, o, 64);
        if (lane == 0) v = relu_(dis[wv] * (__half2float(zs1[wv]) + s) + b4[0]);
    }
    __shared__ float wsum[4];
    if (lane == 0) wsum[t >> 6] = v;
    __syncthreads();
    if (t == 0) partial[blockIdx.x] = wsum[0] + wsum[1] + wsum[2] + wsum[3];
}

// ---- final: out[0] = sum(partial) / n ; one block ----
__global__ __launch_bounds__(1024) void k_final(const float* __restrict__ partial, float* __restrict__ out,
                                                int nb, int n) {
    const int t = threadIdx.x;
    float s = 0.f;
    for (int i = t; i < nb; i += 1024) s += partial[i];
#pragma unroll
    for (int o = 32; o > 0; o >>= 1) s += __shfl_xor(s, o, 64);
    __shared__ float wsum[16];
    if ((t & 63) == 0) wsum[t >> 6] = s;
    __syncthreads();
    if (t == 0) {
        float tot = 0.f;
#pragma unroll
        for (int k = 0; k < 16; ++k) tot += wsum[k];
        out[0] = tot / (float)n;
    }
}

static inline size_t align_up(size_t x) { return (x + 255) & ~(size_t)255; }

extern "C" void kernel_launch(void* const* d_in, const int* in_sizes, int n_in,
                              void* d_out, int out_size, void* d_ws, size_t ws_size,
                              hipStream_t stream) {
    const float* vf  = (const float*)d_in[0];   // [N,128]
    const int*   edg = (const int*)d_in[1];     // [2,E] int32
    const float* w   = (const float*)d_in[2];   // [E]
    const float* W1  = (const float*)d_in[3];
    const float* b1  = (const float*)d_in[4];
    const float* W2  = (const float*)d_in[5];
    const float* b2  = (const float*)d_in[6];
    const float* W3  = (const float*)d_in[7];
    const float* b3  = (const float*)d_in[8];
    const float* W4  = (const float*)d_in[9];
    const float* b4  = (const float*)d_in[10];
    float* out = (float*)d_out;

    const int n = in_sizes[0] / 128;   // 100000
    const int E = in_sizes[2];         // 6400000
    const int* src = edg;
    const int* dst = edg + E;
    const int nbuck = (n + BSIZE - 1) >> BSHIFT;   // 782
    const int gB = (E + FCHUNK - 1) / FCHUNK;      // 782
    const size_t EPAD = (size_t)E + (size_t)gB * nbuck * (PADQ - 1) + 1024;  // worst-case padded

    char* ws = (char*)d_ws;
    size_t off = 0;
    int*                gbcnt   = (int*)(ws + off);                off += align_up((size_t)nbuck * 4);
    int*                brow    = (int*)(ws + off);                off += align_up((size_t)(nbuck + 1) * 4);
    int*                bcur    = (int*)(ws + off);                off += align_up((size_t)nbuck * 4);
    int*                rs      = (int*)(ws + off);                off += align_up((size_t)n * 4);
    int*                re      = (int*)(ws + off);                off += align_up((size_t)n * 4);
    float*              dis     = (float*)(ws + off);              off += align_up((size_t)n * 4);
    float*              partial = (float*)(ws + off);              off += align_up((size_t)((n + 3) / 4 + 1) * 4);
    unsigned long long* ep      = (unsigned long long*)(ws + off); off += align_up(EPAD * 8);
    __half*             zsb     = (__half*)(ws + off);             off += align_up((size_t)n * 16 * 2);
    float*              acc     = (float*)(ws + off);              off += align_up((size_t)n * 16 * 4);
    __half*             zs1     = zsb;   // layer-4 dense output aliases zs (only n halves used)
    (void)ws_size;

    const int gD16 = (n + 15) / 16;                      // dense FO=16: 16 nodes/block
    const int gN = (n + 255) / 256;
    const int gW = (n + 3) / 4;                          // wave-per-node kernels
    const unsigned* epc = (const unsigned*)ep;           // 4B post-sort view

    k_zero<<<(nbuck + 255) / 256, 256, 0, stream>>>(gbcnt, nbuck);
    k_histA<<<gB, FBLK, 0, stream>>>(dst, gbcnt, E, nbuck);
    k_scanA<<<1, 1024, 0, stream>>>(gbcnt, brow, bcur, nbuck);
    k_fill<<<gB, FBLK, 0, stream>>>(src, dst, w, bcur, ep, E, nbuck);
    k_sortB<<<nbuck, SBLK, 0, stream>>>(ep, brow, dis, rs, re, n);

    // layer 1: 128 -> 16
    k_dense<128, 16, false><<<gD16, 256, 0, stream>>>(vf, W1, nullptr, dis, zsb, n);
    k_agg16<<<gW, 256, 0, stream>>>(epc, rs, re, dis, zsb, acc, n);
    // layer 2: 16 -> 16
    k_dense<16, 16, true><<<gD16, 256, 0, stream>>>(acc, W2, b1, dis, zsb, n);
    k_agg16<<<gW, 256, 0, stream>>>(epc, rs, re, dis, zsb, acc, n);
    // layer 3: 16 -> 16
    k_dense<16, 16, true><<<gD16, 256, 0, stream>>>(acc, W3, b2, dis, zsb, n);
    k_agg16<<<gW, 256, 0, stream>>>(epc, rs, re, dis, zsb, acc, n);
    // layer 4: 16 -> 1, then aggregation + relu+bias into per-block partials
    k_dense<16, 1, true><<<gN, 256, 0, stream>>>(acc, W4, b3, dis, zs1, n);
    k_agg1<<<gW, 256, 0, stream>>>(epc, rs, re, dis, zs1, b4, partial, n);
    k_final<<<1, 1024, 0, stream>>>(partial, out, gW, n);
}